// Round 8
// baseline (1305.180 us; speedup 1.0000x reference)
//
#include <hip/hip_runtime.h>

// LSTM, B=512 x T=1024, H=100, input_size=1.  MFMA persistent-RNN, v3.
//
// R7 post-mortem: 16x16x32 MFMA costs ~19.4 cyc PER SIMD (m06: 2075 TF
// = 4.85 cyc/CU). R7's critical SIMD issued 96 MFMAs/step = 1860 cyc —
// that WAS the step time. Lever: precision terms. This version uses
//   W = Whi + 2^-12 * WloScaled   (both fp16; exact split, lo prescaled
//                                  x4096 to stay in fp16 normal range)
//   h = single fp16               (2^-11 dynamic rounding, contractive)
// -> 2 MFMAs per (tile,kt) instead of 3: 200/step, critical SIMD 56.
// 8 waves (block 512): waves 0-6 hold 3 M-tiles, wave 7 holds 4; wave 6
// additionally does the W_out projection (phase C), one step behind.
// Verified layouts (m89, dtype-independent): A[m=lane&15][k=quad*8+j];
// B[k=quad*8+j][n=lane&15]; D[row=quad*4+reg][col=lane&15].

#define HID   100
#define TLEN  1024
#define BLOCK 512   // 8 waves

typedef __attribute__((ext_vector_type(8))) _Float16 half8;
typedef __attribute__((ext_vector_type(4))) float f32x4;

__global__ __launch_bounds__(BLOCK) void lstm_fp16(
    const float* __restrict__ input,   // [B, T]
    const float* __restrict__ W_ih,    // [4H]
    const float* __restrict__ W_hh,    // [4H, H]
    const float* __restrict__ b_ih,    // [4H]
    const float* __restrict__ b_hh,    // [4H]
    const float* __restrict__ W_out,   // [H]
    const float* __restrict__ b_out,   // [1]
    float* __restrict__ out)           // [B, T]
{
    const int tid  = threadIdx.x;
    const int b0   = blockIdx.x * 2;
    const int wv   = tid >> 6;
    const int lane = tid & 63;
    const int col  = lane & 15;        // MFMA m (A row) / D col
    const int quad = lane >> 4;        // MFMA k-block / D row-block
    const int nb   = col & 1;          // batch slot (cols>=2 garbage, unread)

    __shared__ __align__(16) float    in_s[2][TLEN];   // 8 KB
    __shared__ __align__(16) float    g_s[2][400];     // gates (b, row)
    __shared__ __align__(16) float    h_s[2][104];     // fp32 h for phase C
    __shared__ __align__(16) _Float16 BH[2][128];      // fp16 h, k-padded

    // Stage inputs (coalesced); zero BH (covers h0=0 and k in [100,128)).
    for (int i = tid; i < TLEN; i += BLOCK) {
        in_s[0][i] = input[(b0 + 0) * TLEN + i];
        in_s[1][i] = input[(b0 + 1) * TLEN + i];
    }
    if (tid < 256) ((_Float16*)BH)[tid] = (_Float16)0.f;

    // ---- Persistent W_hh A-fragments: exact fp16 hi/lo split, once.
    const bool four  = (wv == 7);
    const int  tbase = four ? 21 : 3 * wv;      // tiles [tbase, tbase+3(+1))
    half8 wHi[4][4], wLo[4][4];                 // [tile][kt]
    #pragma unroll
    for (int m = 0; m < 4; ++m) {
        int mt = tbase + m; if (mt > 24) mt = 24;    // 3-tile waves: slot 3 unused
        const int r = 16 * mt + col;                 // A row = lane&15
        #pragma unroll
        for (int kt = 0; kt < 4; ++kt) {
            half8 hi, lo;
            #pragma unroll
            for (int j = 0; j < 8; ++j) {
                const int k = 32 * kt + 8 * quad + j;    // A k = quad*8+j
                float w = (k < HID) ? W_hh[r * HID + k] : 0.f;
                _Float16 wh = (_Float16)w;
                hi[j] = wh;
                lo[j] = (_Float16)((w - (float)wh) * 4096.f);  // prescale: normal range
            }
            // opacity barrier: forbid remat/sink into the t-loop (R2 lesson)
            asm volatile("" : "+v"(((int*)&hi)[0]), "+v"(((int*)&hi)[1]),
                              "+v"(((int*)&hi)[2]), "+v"(((int*)&hi)[3]));
            asm volatile("" : "+v"(((int*)&lo)[0]), "+v"(((int*)&lo)[1]),
                              "+v"(((int*)&lo)[2]), "+v"(((int*)&lo)[3]));
            wHi[m][kt] = hi; wLo[m][kt] = lo;
        }
    }

    // ---- Phase-B constants (threads 0..199: batch pb, unit pj)
    const int pb = (tid >= 100) ? 1 : 0;
    const int pj = (tid < 200) ? (tid - pb * 100) : 0;
    float wi[4], bi[4];
    #pragma unroll
    for (int g = 0; g < 4; ++g) {
        wi[g] = W_ih[g * 100 + pj];
        bi[g] = b_ih[g * 100 + pj] + b_hh[g * 100 + pj];
    }

    // ---- Phase-C constants (wave 6)
    float wo0 = 0.f, wo1 = 0.f, bo = 0.f;
    if (wv == 6) {
        wo0 = W_out[lane];                          // lane<64<100
        wo1 = (lane < HID - 64) ? W_out[64 + lane] : 0.f;
        bo  = b_out[0];
    }

    float c = 0.f;                                  // cell state (phase-B threads)
    __syncthreads();

    for (int t = 0; t < TLEN; ++t) {
        // ---- Phase C (wave 6): out[t-1] from stable h_s; overlaps MFMA window.
        // Global-store ack drains ~1100 cyc before this wave's barrier -> free.
        if (wv == 6 && t > 0) {
            float p = h_s[0][lane] * wo0;
            float q = h_s[1][lane] * wo0;
            if (lane < HID - 64) {
                p = fmaf(h_s[0][64 + lane], wo1, p);
                q = fmaf(h_s[1][64 + lane], wo1, q);
            }
            #pragma unroll
            for (int off = 32; off > 0; off >>= 1) {
                p += __shfl_down(p, off);
                q += __shfl_down(q, off);
            }
            if (lane == 0) {
                out[(b0 + 0) * TLEN + (t - 1)] = p + bo;
                out[(b0 + 1) * TLEN + (t - 1)] = q + bo;
            }
        }

        // ---- MFMA window: gates = W . h_{t-1}
        half8 bh[4];
        #pragma unroll
        for (int kt = 0; kt < 4; ++kt)               // 4 ds_read_b128, 8 addrs,
            bh[kt] = *(const half8*)&BH[nb][32 * kt + 8 * quad];  // disjoint banks

        f32x4 aH0 = {0,0,0,0}, aH1 = {0,0,0,0}, aH2 = {0,0,0,0}, aH3 = {0,0,0,0};
        f32x4 aL0 = {0,0,0,0}, aL1 = {0,0,0,0}, aL2 = {0,0,0,0}, aL3 = {0,0,0,0};
        #pragma unroll
        for (int kt = 0; kt < 4; ++kt) {
            aH0 = __builtin_amdgcn_mfma_f32_16x16x32_f16(wHi[0][kt], bh[kt], aH0, 0, 0, 0);
            aL0 = __builtin_amdgcn_mfma_f32_16x16x32_f16(wLo[0][kt], bh[kt], aL0, 0, 0, 0);
            aH1 = __builtin_amdgcn_mfma_f32_16x16x32_f16(wHi[1][kt], bh[kt], aH1, 0, 0, 0);
            aL1 = __builtin_amdgcn_mfma_f32_16x16x32_f16(wLo[1][kt], bh[kt], aL1, 0, 0, 0);
            aH2 = __builtin_amdgcn_mfma_f32_16x16x32_f16(wHi[2][kt], bh[kt], aH2, 0, 0, 0);
            aL2 = __builtin_amdgcn_mfma_f32_16x16x32_f16(wLo[2][kt], bh[kt], aL2, 0, 0, 0);
            if (four) {
                aH3 = __builtin_amdgcn_mfma_f32_16x16x32_f16(wHi[3][kt], bh[kt], aH3, 0, 0, 0);
                aL3 = __builtin_amdgcn_mfma_f32_16x16x32_f16(wLo[3][kt], bh[kt], aL3, 0, 0, 0);
            }
        }

        // Epilogue: gate = aH + 2^-12 * aL. D rows quad*4..+3 contiguous ->
        // one b128 store per tile; g_s stride 400 (bank +16) -> conflict-free.
        if (col < 2) {
            const float s = 2.44140625e-4f;          // 2^-12
            f32x4 g0 = aH0 + aL0 * s;
            f32x4 g1 = aH1 + aL1 * s;
            f32x4 g2 = aH2 + aL2 * s;
            *(f32x4*)(&g_s[col][16 * (tbase + 0) + 4 * quad]) = g0;
            *(f32x4*)(&g_s[col][16 * (tbase + 1) + 4 * quad]) = g1;
            *(f32x4*)(&g_s[col][16 * (tbase + 2) + 4 * quad]) = g2;
            if (four) {
                f32x4 g3 = aH3 + aL3 * s;
                *(f32x4*)(&g_s[col][16 * (tbase + 3) + 4 * quad]) = g3;
            }
        }
        __syncthreads();

        // ---- Cell window: pointwise LSTM (200 threads), writes h_t
        if (tid < 200) {
            const float x = in_s[pb][t];
            float ig = fmaf(x, wi[0], bi[0]) + g_s[pb][pj];
            float fg = fmaf(x, wi[1], bi[1]) + g_s[pb][100 + pj];
            float gg = fmaf(x, wi[2], bi[2]) + g_s[pb][200 + pj];
            float og = fmaf(x, wi[3], bi[3]) + g_s[pb][300 + pj];
            float is = 1.f / (1.f + __expf(-ig));
            float fs = 1.f / (1.f + __expf(-fg));
            float os = 1.f / (1.f + __expf(-og));
            float gt = 1.f - 2.f / (__expf(2.f * gg) + 1.f);   // stable tanh
            c = fmaf(fs, c, is * gt);
            float hv = os * (1.f - 2.f / (__expf(2.f * c) + 1.f));
            h_s[pb][pj] = hv;                 // fp32 copy for phase C
            BH[pb][pj]  = (_Float16)hv;       // fp16 B operand for next step
        }
        __syncthreads();
    }

    // Final output: t = TLEN-1
    if (wv == 6) {
        float p = h_s[0][lane] * wo0;
        float q = h_s[1][lane] * wo0;
        if (lane < HID - 64) {
            p = fmaf(h_s[0][64 + lane], wo1, p);
            q = fmaf(h_s[1][64 + lane], wo1, q);
        }
        #pragma unroll
        for (int off = 32; off > 0; off >>= 1) {
            p += __shfl_down(p, off);
            q += __shfl_down(q, off);
        }
        if (lane == 0) {
            out[(b0 + 0) * TLEN + (TLEN - 1)] = p + bo;
            out[(b0 + 1) * TLEN + (TLEN - 1)] = q + bo;
        }
    }
}

extern "C" void kernel_launch(void* const* d_in, const int* in_sizes, int n_in,
                              void* d_out, int out_size, void* d_ws, size_t ws_size,
                              hipStream_t stream) {
    const float* input = (const float*)d_in[0];
    const float* W_ih  = (const float*)d_in[1];
    const float* W_hh  = (const float*)d_in[2];
    const float* b_ih  = (const float*)d_in[3];
    const float* b_hh  = (const float*)d_in[4];
    const float* W_out = (const float*)d_in[5];
    const float* b_out = (const float*)d_in[6];
    float* out = (float*)d_out;

    const int B = in_sizes[0] / TLEN;  // 512
    lstm_fp16<<<B / 2, BLOCK, 0, stream>>>(input, W_ih, W_hh, b_ih, b_hh,
                                           W_out, b_out, out);
}